// Round 7
// baseline (1780.975 us; speedup 1.0000x reference)
//
#include <hip/hip_runtime.h>
#include <math.h>

// OscillatorEngine on MI355X — round 7: ONE persistent kernel.
// N=8192, D_IN=512, D_H=1024, 8 factions of 1024, dc=256, SYNC=.15, DEBATE=.15
//
// Algebraic restructuring (exact in real arithmetic):
//  interactions[i] = (K/N)(sin p_i * Sc_i - cos p_i * Ss_i)   [one streaming pass over C]
//  cell_hiddens rank-2 in per-cell (a_i, b_i)  ->  pre1[i] = a_i u0 + b_i u1 + u2
//  weighted = (sum_i w_i tanh(pre1_i)) @ w_enc2 + b_enc2      [softmax weights sum to 1]
//
// Round-7: rounds 2-6 showed ±5-8 µs cross-run noise and ~35-50 µs of unexplained
// inter-kernel gap (sum of ideal kernel times ≈ 55 µs vs 89-108 measured). Fuse all
// phases into one kernel with a device-scope grid barrier. 1024 blocks x 256 thr,
// __launch_bounds__(256,4) pins 4 blocks/CU => guaranteed co-residency for the
// barrier. Phase bodies are EXACT round-2 code.

#define NC   8192
#define DH   1024
#define DIN  512
#define NBLK 1024

using f4 = __attribute__((ext_vector_type(4))) float;

// workspace layout (float offsets)
constexpr int IMG = 0, TENS = 6;
constexpr int SN0 = 32;                          // sin(old phases) [8192]
constexpr int CN0 = SN0 + NC;
constexpr int SNN = CN0 + NC;                    // sin(new phases)
constexpr int CNN = SNN + NC;
constexpr int UPART  = CNN + NC;                 // [16][3][1024]
constexpr int TPART  = UPART + 16 * 3 * DH;      // [128][1024]
constexpr int W2PART = TPART + 128 * DH;         // [16][1024]
constexpr int OPART  = W2PART + 16 * DH;         // [16][512]

__device__ __forceinline__ float frcp(float x) { return __builtin_amdgcn_rcpf(x); }
__device__ __forceinline__ float sigm(float x) { return frcp(1.f + __expf(-x)); }
__device__ __forceinline__ float ftanh(float x) { return 1.f - 2.f * frcp(__expf(2.f * x) + 1.f); }

// ---- device-scope hierarchical grid barrier (sense-reversing, 32 groups x 32) ----
__device__ unsigned g_cnt[32];
__device__ unsigned g_root;
__device__ unsigned g_gen;

__device__ __forceinline__ void gsync() {
  __syncthreads();
  if (threadIdx.x == 0) {
    unsigned gen = __hip_atomic_load(&g_gen, __ATOMIC_RELAXED, __HIP_MEMORY_SCOPE_AGENT);
    int grp = blockIdx.x >> 5;
    unsigned a = __hip_atomic_fetch_add(&g_cnt[grp], 1u, __ATOMIC_ACQ_REL,
                                        __HIP_MEMORY_SCOPE_AGENT);
    bool done = false;
    if (a == 31u) {
      unsigned r = __hip_atomic_fetch_add(&g_root, 1u, __ATOMIC_ACQ_REL,
                                          __HIP_MEMORY_SCOPE_AGENT);
      if (r == 31u) {   // last block overall: reset counters, bump generation
        __hip_atomic_store(&g_root, 0u, __ATOMIC_RELAXED, __HIP_MEMORY_SCOPE_AGENT);
        #pragma unroll
        for (int i = 0; i < 32; ++i)
          __hip_atomic_store(&g_cnt[i], 0u, __ATOMIC_RELAXED, __HIP_MEMORY_SCOPE_AGENT);
        __hip_atomic_fetch_add(&g_gen, 1u, __ATOMIC_RELEASE, __HIP_MEMORY_SCOPE_AGENT);
        done = true;
      }
    }
    if (!done) {
      while (__hip_atomic_load(&g_gen, __ATOMIC_ACQUIRE, __HIP_MEMORY_SCOPE_AGENT) == gen)
        __builtin_amdgcn_s_sleep(16);
    }
  }
  __syncthreads();
}

__global__ __launch_bounds__(256, 4) void k_all(
    const float* __restrict__ x,       const float* __restrict__ phases,
    const float* __restrict__ omegas,  const float* __restrict__ coupling,
    const float* __restrict__ Kp,      const float* __restrict__ w_p2h,
    const float* __restrict__ b_p2h,   const float* __restrict__ w_enc1,
    const float* __restrict__ b_enc1,  const float* __restrict__ w_enc2,
    const float* __restrict__ b_enc2,  const float* __restrict__ w_out,
    const float* __restrict__ b_out,   const int* __restrict__ step,
    float* __restrict__ W,             float* __restrict__ out) {
  __shared__ float sh4[4];
  __shared__ float shp[4][4];
  __shared__ float shS[4][8], shC[4][8], shD[4];
  __shared__ float bcS[8], bcC[8], bc2[6];
  __shared__ float ts[64], wvv[64];

  const int b = blockIdx.x, t = threadIdx.x;
  const int lane = t & 63, w = t >> 6;

  // ---------------- P0: sincos table, ||x||, u-partials (round-2 k_prep_up) ------
  if (b < 97) {
    if (b < 32) {
      int i = b * 256 + t;
      float s, c;
      sincosf(phases[i], &s, &c);
      W[SN0 + i] = s;
      W[CN0 + i] = c;
    } else if (b == 32) {
      float x0 = x[t], x1 = x[t + 256];
      float v = x0 * x0 + x1 * x1;
      #pragma unroll
      for (int m = 1; m < 64; m <<= 1) v += __shfl_xor(v, m, 64);
      if (lane == 0) sh4[w] = v;
      __syncthreads();
      if (t == 0) W[IMG] = sqrtf(sh4[0] + sh4[1] + sh4[2] + sh4[3]);
    } else {
      int idx = b - 33;       // 0..63
      int hb = idx & 3;       // 4 h-groups of 256
      int dy = idx >> 2;      // 16 d-chunks
      int h = hb * 256 + t;
      float a0 = 0.f, a1 = 0.f, a2 = 0.f;
      for (int d = dy * 64; d < dy * 64 + 64; ++d) {
        float r = w_enc1[d * DH + h];
        a0 = fmaf(w_p2h[d], r, a0);
        a1 = fmaf(w_p2h[DH + d], r, a1);
        a2 = fmaf(b_p2h[d], r, a2);
      }
      for (int k = dy * 32; k < dy * 32 + 32; ++k)
        a2 = fmaf(x[k], w_enc1[(DH + k) * DH + h], a2);
      if (dy == 0) a2 += b_enc1[h];
      float* up = W + UPART + dy * 3 * DH;
      up[h] = a0;
      up[DH + h] = a1;
      up[2 * DH + h] = a2;
    }
  }
  gsync();

  // ---------------- P1: coupling stream, 4 row-pairs per block (round-2 k_rows) --
  {
    const f4* s4 = (const f4*)(W + SN0);
    const f4* c4 = (const f4*)(W + CN0);
    for (int p = 0; p < 4; ++p) {
      __syncthreads();   // protect shp against WAR across pairs
      int row0 = (b + NBLK * p) * 2;
      const f4* c0 = (const f4*)(coupling + (size_t)row0 * NC);
      const f4* c1 = (const f4*)(coupling + (size_t)(row0 + 1) * NC);
      float sc0 = 0.f, ss0 = 0.f, sc1 = 0.f, ss1 = 0.f;
      #pragma unroll 4
      for (int k = 0; k < 8; ++k) {
        int idx = k * 256 + t;
        f4 cc = c4[idx];
        f4 sv = s4[idx];
        f4 v0 = __builtin_nontemporal_load(c0 + idx);
        f4 v1 = __builtin_nontemporal_load(c1 + idx);
        #pragma unroll
        for (int e = 0; e < 4; ++e) {
          float g0 = sigm(v0[e]);
          sc0 = fmaf(g0, cc[e], sc0);
          ss0 = fmaf(g0, sv[e], ss0);
          float g1 = sigm(v1[e]);
          sc1 = fmaf(g1, cc[e], sc1);
          ss1 = fmaf(g1, sv[e], ss1);
        }
      }
      #pragma unroll
      for (int m = 1; m < 64; m <<= 1) {
        sc0 += __shfl_xor(sc0, m, 64);
        ss0 += __shfl_xor(ss0, m, 64);
        sc1 += __shfl_xor(sc1, m, 64);
        ss1 += __shfl_xor(ss1, m, 64);
      }
      if (lane == 0) { shp[w][0] = sc0; shp[w][1] = ss0; shp[w][2] = sc1; shp[w][3] = ss1; }
      __syncthreads();
      if (t < 2) {
        float sc = shp[0][2 * t] + shp[1][2 * t] + shp[2][2 * t] + shp[3][2 * t];
        float ss = shp[0][2 * t + 1] + shp[1][2 * t + 1] + shp[2][2 * t + 1] + shp[3][2 * t + 1];
        int row = row0 + t;
        float kk = Kp[0];
        float si = W[SN0 + row], ci = W[CN0 + row];
        float inter = (kk / (float)NC) * (si * sc - ci * ss);
        float dtheta = omegas[row] + inter + 0.1f * W[IMG];
        float pn = phases[row] + 0.1f * dtheta;   // mod 2pi dropped: only sin/cos used
        float s, c;
        sincosf(pn, &s, &c);
        W[SNN + row] = s;
        W[CNN + row] = c;
      }
    }
  }
  gsync();

  // ---------------- P2: redundant stats + u-reduction + cells (128 blocks) -------
  if (b < 128) {
    const f4* s4 = (const f4*)(W + SNN);
    const f4* c4 = (const f4*)(W + CNN);
    float sp[8], cp[8];
    #pragma unroll
    for (int f = 0; f < 8; ++f) {
      f4 sv = s4[f * 256 + t];
      f4 cv = c4[f * 256 + t];
      sp[f] = (sv[0] + sv[1]) + (sv[2] + sv[3]);
      cp[f] = (cv[0] + cv[1]) + (cv[2] + cv[3]);
    }
    #pragma unroll
    for (int f = 0; f < 8; ++f) {
      #pragma unroll
      for (int m = 1; m < 64; m <<= 1) {
        sp[f] += __shfl_xor(sp[f], m, 64);
        cp[f] += __shfl_xor(cp[f], m, 64);
      }
    }
    if (lane == 0) {
      #pragma unroll
      for (int f = 0; f < 8; ++f) { shS[w][f] = sp[f]; shC[w][f] = cp[f]; }
    }
    __syncthreads();
    if (t == 0) {
      float ssum = 0.f, csum = 0.f;
      #pragma unroll
      for (int f = 0; f < 8; ++f) {
        float S = (shS[0][f] + shS[1][f]) + (shS[2][f] + shS[3][f]);
        float C = (shC[0][f] + shC[1][f]) + (shC[2][f] + shC[3][f]);
        bcS[f] = S * (1.f / 1024.f);
        bcC[f] = C * (1.f / 1024.f);
        ssum += S;
        csum += C;
      }
      float sbar = ssum * (1.f / (float)NC);
      float cbar = csum * (1.f / (float)NC);
      float mp = atan2f(sbar, cbar);
      bc2[0] = sbar; bc2[1] = cbar; bc2[2] = cosf(mp); bc2[3] = sinf(mp);
      if (b == 0) {
        float r = sqrtf(cbar * cbar + sbar * sbar);
        W[TENS] = fabsf(r - 0.5f) * 2.f;
      }
    }
    __syncthreads();
    float mpc = bc2[2], mps = bc2[3];
    float d = 0.f;
    #pragma unroll
    for (int k = 0; k < 8; ++k) {
      f4 sv = s4[k * 256 + t];
      f4 cv = c4[k * 256 + t];
      #pragma unroll
      for (int e = 0; e < 4; ++e) {
        float coh = cv[e] * mpc + sv[e] * mps;
        d += __expf(5.f * coh - 5.f);   // shift by const 5: cancels in normalization
      }
    }
    #pragma unroll
    for (int m = 1; m < 64; m <<= 1) d += __shfl_xor(d, m, 64);
    if (lane == 0) shD[w] = d;
    __syncthreads();
    if (t == 0) bc2[4] = 1.0f / ((shD[0] + shD[1]) + (shD[2] + shD[3]));
    __syncthreads();
    float invden = bc2[4];
    float sbar = bc2[0], cbar = bc2[1];
    float u0[4], u1[4], u2[4], acc[4] = {0.f, 0.f, 0.f, 0.f};
    #pragma unroll
    for (int k = 0; k < 4; ++k) {
      int h = t + k * 256;
      float v0 = 0.f, v1 = 0.f, v2 = 0.f;
      #pragma unroll
      for (int p = 0; p < 16; ++p) {
        const float* up = W + UPART + p * 3 * DH;
        v0 += up[h];
        v1 += up[DH + h];
        v2 += up[2 * DH + h];
      }
      u0[k] = v0; u1[k] = v1; u2[k] = v2;
    }
    bool debate = step[0] > 5;
    int i0 = b * 64;
    int f = i0 >> 10;                     // 64-cell chunk never crosses a faction
    float Sf = bcS[f], Cf = bcC[f];
    bool deb = debate && ((i0 & 1023) < 256);  // dc = FS/4 = 256; uniform per chunk
    for (int j = 0; j < 64; ++j) {
      int i = i0 + j;
      float s = W[SNN + i], c = W[CNN + i];   // wave-uniform loads
      float a = fmaf(0.15f, Sf, 0.85f * s);
      float bb = fmaf(0.15f, Cf, 0.85f * c);
      if (deb) {
        a = fmaf(0.15f, sbar, 0.85f * a);
        bb = fmaf(0.15f, cbar, 0.85f * bb);
      }
      float coh = c * mpc + s * mps;
      float wgt = __expf(5.f * coh - 5.f) * invden;
      #pragma unroll
      for (int k = 0; k < 4; ++k) {
        float pre = fmaf(a, u0[k], fmaf(bb, u1[k], u2[k]));
        acc[k] = fmaf(wgt, ftanh(pre), acc[k]);
      }
    }
    #pragma unroll
    for (int k = 0; k < 4; ++k) W[TPART + b * DH + t + k * 256] = acc[k];
  }
  gsync();

  // ---------------- P3: t_sum reduce + matvec w_enc2 (64 blocks) -----------------
  if (b < 64) {
    int cb = b & 3, hb = b >> 2;
    if (t < 64) {
      int h = hb * 64 + t;
      float v = 0.f;
      for (int p = 0; p < 128; ++p) v += W[TPART + p * DH + h];
      ts[t] = v;
    }
    __syncthreads();
    int c = cb * 256 + t;
    float acc = (hb == 0) ? b_enc2[c] : 0.f;
    #pragma unroll 8
    for (int j = 0; j < 64; ++j) acc = fmaf(ts[j], w_enc2[(hb * 64 + j) * DH + c], acc);
    W[W2PART + hb * DH + c] = acc;
  }
  gsync();

  // ---------------- P4: weighted reduce + matvec w_out (32 blocks) ---------------
  if (b < 32) {
    int ob = b & 1, cb = b >> 1;
    if (t < 64) {
      int c = cb * 64 + t;
      float v = 0.f;
      #pragma unroll
      for (int p = 0; p < 16; ++p) v += W[W2PART + p * DH + c];
      wvv[t] = v;
    }
    __syncthreads();
    int o = ob * 256 + t;
    float acc = 0.f;
    #pragma unroll 8
    for (int j = 0; j < 64; ++j) acc = fmaf(wvv[j], w_out[(cb * 64 + j) * DIN + o], acc);
    W[OPART + cb * DIN + o] = acc;
  }
  gsync();

  // ---------------- P5: final reduce + bias + tension (2 blocks) -----------------
  if (b < 2) {
    int o = b * 256 + t;
    float acc = b_out[o];
    #pragma unroll
    for (int p = 0; p < 16; ++p) acc += W[OPART + p * DIN + o];
    out[o] = acc;
    if (o == 0) out[DIN] = W[TENS];
  }
}

extern "C" void kernel_launch(void* const* d_in, const int* in_sizes, int n_in,
                              void* d_out, int out_size, void* d_ws, size_t ws_size,
                              hipStream_t stream) {
  (void)in_sizes; (void)n_in; (void)out_size; (void)ws_size;
  const float* x        = (const float*)d_in[0];
  const float* phases   = (const float*)d_in[1];
  const float* omegas   = (const float*)d_in[2];
  const float* coupling = (const float*)d_in[3];
  const float* Kp       = (const float*)d_in[4];
  const float* w_p2h    = (const float*)d_in[5];
  const float* b_p2h    = (const float*)d_in[6];
  const float* w_enc1   = (const float*)d_in[7];
  const float* b_enc1   = (const float*)d_in[8];
  const float* w_enc2   = (const float*)d_in[9];
  const float* b_enc2   = (const float*)d_in[10];
  const float* w_out    = (const float*)d_in[11];
  const float* b_out    = (const float*)d_in[12];
  const int*   step     = (const int*)d_in[13];
  float* W   = (float*)d_ws;
  float* out = (float*)d_out;

  k_all<<<NBLK, 256, 0, stream>>>(x, phases, omegas, coupling, Kp, w_p2h, b_p2h,
                                  w_enc1, b_enc1, w_enc2, b_enc2, w_out, b_out,
                                  step, W, out);
}

// Round 8
// 91.048 us; speedup vs baseline: 19.5607x; 19.5607x over previous
//
#include <hip/hip_runtime.h>
#include <math.h>

// OscillatorEngine on MI355X — round 8.
// Base = round 2 EXACTLY (88.9 µs champion; k_rows/stats/cells byte-identical).
// Deltas: (1) uprep f4-vectorized (latency-bound prep on critical path);
//         (2) k_final folded into k_out via last-block completion (7->6 launches).
// R7 lesson: grid-wide atomic barriers on 8 non-coherent XCDs cost ~300 µs/sync
// (1024 agent-scope pollers serialize at the MALL) — never again. The 32-block
// counter here is 2 orders of magnitude smaller and fires once.

#define NC   8192
#define DH   1024
#define DIN  512

using f4 = __attribute__((ext_vector_type(4))) float;

// workspace layout (float offsets)
constexpr int IMG = 0, TENS = 6, CNT = 7;
constexpr int SN0 = 32;                          // sin(old phases) [8192]
constexpr int CN0 = SN0 + NC;
constexpr int SNN = CN0 + NC;                    // sin(new phases)
constexpr int CNN = SNN + NC;
constexpr int UPART  = CNN + NC;                 // [16][3][1024]
constexpr int UFIN   = UPART + 16 * 3 * DH;      // [3][1024]
constexpr int TPART  = UFIN + 3 * DH;            // [128][1024]
constexpr int W2PART = TPART + 128 * DH;         // [16][1024]
constexpr int OPART  = W2PART + 16 * DH;         // [16][512]

__device__ __forceinline__ float frcp(float x) { return __builtin_amdgcn_rcpf(x); }
__device__ __forceinline__ float sigm(float x) { return frcp(1.f + __expf(-x)); }
__device__ __forceinline__ float ftanh(float x) { return 1.f - 2.f * frcp(__expf(2.f * x) + 1.f); }

template <int BS>
__device__ __forceinline__ float block_reduce(float v, float* sh) {
  #pragma unroll
  for (int m = 1; m < 64; m <<= 1) v += __shfl_xor(v, m, 64);
  constexpr int NW = BS / 64;
  int lane = threadIdx.x & 63, w = threadIdx.x >> 6;
  if (lane == 0) sh[w] = v;
  __syncthreads();
  if (w == 0) {
    float x = (lane < NW) ? sh[lane] : 0.f;
    #pragma unroll
    for (int m = 1; m < NW; m <<= 1) x += __shfl_xor(x, m, 64);
    if (lane == 0) sh[0] = x;
  }
  __syncthreads();
  float r = sh[0];
  __syncthreads();
  return r;
}

// K1: sincos(old) [b<32], ||x|| [b==32], u-partials f4-vectorized [b in 33..48]
__global__ __launch_bounds__(256) void k_prep_up(const float* __restrict__ phases,
                                                 const float* __restrict__ x,
                                                 const float* __restrict__ w_p2h,
                                                 const float* __restrict__ b_p2h,
                                                 const float* __restrict__ w_enc1,
                                                 const float* __restrict__ b_enc1,
                                                 float* __restrict__ W) {
  __shared__ float sh[4];
  int b = blockIdx.x, t = threadIdx.x;
  if (b < 32) {
    int i = b * 256 + t;
    float s, c;
    sincosf(phases[i], &s, &c);
    W[SN0 + i] = s;
    W[CN0 + i] = c;
  } else if (b == 32) {
    float x0 = x[t], x1 = x[t + 256];
    float v = block_reduce<256>(x0 * x0 + x1 * x1, sh);
    if (t == 0) W[IMG] = sqrtf(v);
  } else {
    int dy = b - 33;            // 0..15, d-chunk
    f4 a0 = {0.f, 0.f, 0.f, 0.f}, a1 = a0, a2 = a0;
    for (int d = dy * 64; d < dy * 64 + 64; ++d) {
      f4 r = *(const f4*)(w_enc1 + (size_t)d * DH + 4 * t);
      float s0 = w_p2h[d], s1 = w_p2h[DH + d], s2 = b_p2h[d];
      #pragma unroll
      for (int e = 0; e < 4; ++e) {
        a0[e] = fmaf(s0, r[e], a0[e]);
        a1[e] = fmaf(s1, r[e], a1[e]);
        a2[e] = fmaf(s2, r[e], a2[e]);
      }
    }
    for (int k = dy * 32; k < dy * 32 + 32; ++k) {
      f4 r = *(const f4*)(w_enc1 + (size_t)(DH + k) * DH + 4 * t);
      float xv = x[k];
      #pragma unroll
      for (int e = 0; e < 4; ++e) a2[e] = fmaf(xv, r[e], a2[e]);
    }
    if (dy == 0) {
      f4 bb = *(const f4*)(b_enc1 + 4 * t);
      #pragma unroll
      for (int e = 0; e < 4; ++e) a2[e] += bb[e];
    }
    float* up = W + UPART + dy * 3 * DH;
    *(f4*)(up + 4 * t) = a0;
    *(f4*)(up + DH + 4 * t) = a1;
    *(f4*)(up + 2 * DH + 4 * t) = a2;
  }
}

// K2 (round-2 exact): 2 rows/block, nontemporal, 1-barrier reduce.
__global__ __launch_bounds__(256) void k_rows(const float* __restrict__ coupling,
                                              const float* __restrict__ phases,
                                              const float* __restrict__ omegas,
                                              const float* __restrict__ Kp,
                                              float* __restrict__ W) {
  __shared__ float sh[4][4];
  int t = threadIdx.x;
  int row0 = blockIdx.x * 2;
  const f4* c0 = (const f4*)(coupling + (size_t)row0 * NC);
  const f4* c1 = (const f4*)(coupling + (size_t)(row0 + 1) * NC);
  const f4* s4 = (const f4*)(W + SN0);
  const f4* c4 = (const f4*)(W + CN0);
  float sc0 = 0.f, ss0 = 0.f, sc1 = 0.f, ss1 = 0.f;
  #pragma unroll 4
  for (int k = 0; k < 8; ++k) {
    int idx = k * 256 + t;
    f4 cc = c4[idx];
    f4 sv = s4[idx];
    f4 v0 = __builtin_nontemporal_load(c0 + idx);
    f4 v1 = __builtin_nontemporal_load(c1 + idx);
    #pragma unroll
    for (int e = 0; e < 4; ++e) {
      float g0 = sigm(v0[e]);
      sc0 = fmaf(g0, cc[e], sc0);
      ss0 = fmaf(g0, sv[e], ss0);
      float g1 = sigm(v1[e]);
      sc1 = fmaf(g1, cc[e], sc1);
      ss1 = fmaf(g1, sv[e], ss1);
    }
  }
  #pragma unroll
  for (int m = 1; m < 64; m <<= 1) {
    sc0 += __shfl_xor(sc0, m, 64);
    ss0 += __shfl_xor(ss0, m, 64);
    sc1 += __shfl_xor(sc1, m, 64);
    ss1 += __shfl_xor(ss1, m, 64);
  }
  int lane = t & 63, w = t >> 6;
  if (lane == 0) { sh[w][0] = sc0; sh[w][1] = ss0; sh[w][2] = sc1; sh[w][3] = ss1; }
  __syncthreads();
  if (t < 2) {
    float sc = sh[0][2 * t] + sh[1][2 * t] + sh[2][2 * t] + sh[3][2 * t];
    float ss = sh[0][2 * t + 1] + sh[1][2 * t + 1] + sh[2][2 * t + 1] + sh[3][2 * t + 1];
    int row = row0 + t;
    float kk = Kp[0];
    float si = W[SN0 + row], ci = W[CN0 + row];
    float inter = (kk / (float)NC) * (si * sc - ci * ss);
    float dtheta = omegas[row] + inter + 0.1f * W[IMG];
    float pn = phases[row] + 0.1f * dtheta;   // mod 2pi dropped: only sin/cos consumed
    float s, c;
    sincosf(pn, &s, &c);
    W[SNN + row] = s;
    W[CNN + row] = c;
  }
}

// K3 (round-2 exact): block 0 = stats (3 barriers); blocks 1..3 = u-partial reduce.
__global__ __launch_bounds__(1024) void k_stats_ured(float* __restrict__ W) {
  if (blockIdx.x > 0) {
    int j = (blockIdx.x - 1) * 1024 + threadIdx.x;  // 0..3071
    float v = 0.f;
    #pragma unroll
    for (int p = 0; p < 16; ++p) v += W[UPART + p * 3 * DH + j];
    W[UFIN + j] = v;
    return;
  }
  __shared__ float shS[16], shC[16], shD[16], shMP[2];
  int t = threadIdx.x, lane = t & 63, w = t >> 6;
  int f = w >> 1, half = w & 1;
  int base = f * 1024 + half * 512;
  float s = 0.f, c = 0.f;
  #pragma unroll
  for (int k = 0; k < 8; ++k) {
    int i = base + k * 64 + lane;
    s += W[SNN + i];
    c += W[CNN + i];
  }
  #pragma unroll
  for (int m = 1; m < 64; m <<= 1) {
    s += __shfl_xor(s, m, 64);
    c += __shfl_xor(c, m, 64);
  }
  if (lane == 0) { shS[w] = s; shC[w] = c; }
  __syncthreads();
  if (t == 0) {
    float ssum = 0.f, csum = 0.f;
    #pragma unroll
    for (int ff = 0; ff < 8; ++ff) {
      float S = shS[2 * ff] + shS[2 * ff + 1];
      float C = shC[2 * ff] + shC[2 * ff + 1];
      W[8 + ff] = S * (1.f / 1024.f);    // SFO
      W[16 + ff] = C * (1.f / 1024.f);   // CFO
      ssum += S;
      csum += C;
    }
    float sbar = ssum * (1.f / (float)NC);
    float cbar = csum * (1.f / (float)NC);
    float mp = atan2f(sbar, cbar);
    float mpc = cosf(mp), mps = sinf(mp);
    W[1] = sbar; W[2] = cbar; W[3] = mpc; W[4] = mps;
    float r = sqrtf(cbar * cbar + sbar * sbar);
    W[TENS] = fabsf(r - 0.5f) * 2.f;
    shMP[0] = mpc; shMP[1] = mps;
  }
  __syncthreads();
  float mpc = shMP[0], mps = shMP[1];
  float d = 0.f;
  #pragma unroll
  for (int k = 0; k < 8; ++k) {
    int i = k * 1024 + t;
    float coh = W[CNN + i] * mpc + W[SNN + i] * mps;
    d += __expf(5.f * coh - 5.f);  // shift by const 5: cancels in normalization
  }
  #pragma unroll
  for (int m = 1; m < 64; m <<= 1) d += __shfl_xor(d, m, 64);
  if (lane == 0) shD[w] = d;
  __syncthreads();
  if (t == 0) {
    float D = 0.f;
    #pragma unroll
    for (int ww = 0; ww < 16; ++ww) D += shD[ww];
    W[5] = D;                          // DEN
  }
}

// K4 (round-2 exact): per-cell rank-2 eval + tanh + weighted accumulate.
__global__ __launch_bounds__(256) void k_cells(const int* __restrict__ step,
                                               float* __restrict__ W) {
  int t = threadIdx.x, b = blockIdx.x;
  float u0[4], u1[4], u2[4], acc[4] = {0.f, 0.f, 0.f, 0.f};
  #pragma unroll
  for (int k = 0; k < 4; ++k) {
    int h = t + k * 256;
    u0[k] = W[UFIN + h];
    u1[k] = W[UFIN + DH + h];
    u2[k] = W[UFIN + 2 * DH + h];
  }
  bool debate = step[0] > 5;
  float sbar = W[1], cbar = W[2], mpc = W[3], mps = W[4];
  float invden = 1.0f / W[5];
  int i0 = b * 64;
  int f = i0 >> 10;  // 64-cell chunk never crosses a faction boundary
  float Sf = W[8 + f], Cf = W[16 + f];
  bool deb = debate && ((i0 & 1023) < 256);  // dc = FS/4 = 256; uniform per chunk
  for (int j = 0; j < 64; ++j) {
    int i = i0 + j;
    float s = W[SNN + i], c = W[CNN + i];
    float a = fmaf(0.15f, Sf, 0.85f * s);
    float bb = fmaf(0.15f, Cf, 0.85f * c);
    if (deb) {
      a = fmaf(0.15f, sbar, 0.85f * a);
      bb = fmaf(0.15f, cbar, 0.85f * bb);
    }
    float coh = c * mpc + s * mps;
    float wgt = __expf(5.f * coh - 5.f) * invden;
    #pragma unroll
    for (int k = 0; k < 4; ++k) {
      float pre = fmaf(a, u0[k], fmaf(bb, u1[k], u2[k]));
      acc[k] = fmaf(wgt, ftanh(pre), acc[k]);
    }
  }
  #pragma unroll
  for (int k = 0; k < 4; ++k) W[TPART + b * DH + t + k * 256] = acc[k];
}

// K5 (round-2 exact + counter zero): t_sum reduce + matvec w_enc2.
__global__ __launch_bounds__(256) void k_wv(const float* __restrict__ w_enc2,
                                            const float* __restrict__ b_enc2,
                                            float* __restrict__ W) {
  __shared__ float ts[64];
  int t = threadIdx.x, cb = blockIdx.x, hb = blockIdx.y;
  if (t == 0 && cb == 0 && hb == 0) *(unsigned*)(W + CNT) = 0u;
  if (t < 64) {
    int h = hb * 64 + t;
    float v = 0.f;
    for (int p = 0; p < 128; ++p) v += W[TPART + p * DH + h];
    ts[t] = v;
  }
  __syncthreads();
  int c = cb * 256 + t;
  float acc = (hb == 0) ? b_enc2[c] : 0.f;
  #pragma unroll 8
  for (int j = 0; j < 64; ++j) acc = fmaf(ts[j], w_enc2[(hb * 64 + j) * DH + c], acc);
  W[W2PART + hb * DH + c] = acc;
}

// K6: weighted reduce + matvec w_out; LAST block also does the final reduction
// (fixed summation order -> deterministic, replaces k_final).
__global__ __launch_bounds__(256) void k_out(const float* __restrict__ w_out,
                                             const float* __restrict__ b_out,
                                             float* __restrict__ W,
                                             float* __restrict__ out) {
  __shared__ float wv[64];
  __shared__ int last;
  int t = threadIdx.x, ob = blockIdx.x, cb = blockIdx.y;
  if (t < 64) {
    int c = cb * 64 + t;
    float v = 0.f;
    #pragma unroll
    for (int p = 0; p < 16; ++p) v += W[W2PART + p * DH + c];
    wv[t] = v;
  }
  __syncthreads();
  int o = ob * 256 + t;
  float acc = 0.f;
  #pragma unroll 8
  for (int j = 0; j < 64; ++j) acc = fmaf(wv[j], w_out[(cb * 64 + j) * DIN + o], acc);
  W[OPART + cb * DIN + o] = acc;
  // completion protocol: 32 blocks; last one does the final reduce.
  __syncthreads();
  if (t == 0) {
    unsigned old = __hip_atomic_fetch_add((unsigned*)(W + CNT), 1u,
                                          __ATOMIC_ACQ_REL, __HIP_MEMORY_SCOPE_AGENT);
    last = (old == 31u);
  }
  __syncthreads();
  if (!last) return;
  for (int oo = t; oo < DIN; oo += 256) {
    float a = b_out[oo];
    #pragma unroll
    for (int p = 0; p < 16; ++p) a += W[OPART + p * DIN + oo];
    out[oo] = a;
  }
  if (t == 0) out[DIN] = W[TENS];
}

extern "C" void kernel_launch(void* const* d_in, const int* in_sizes, int n_in,
                              void* d_out, int out_size, void* d_ws, size_t ws_size,
                              hipStream_t stream) {
  (void)in_sizes; (void)n_in; (void)out_size; (void)ws_size;
  const float* x        = (const float*)d_in[0];
  const float* phases   = (const float*)d_in[1];
  const float* omegas   = (const float*)d_in[2];
  const float* coupling = (const float*)d_in[3];
  const float* Kp       = (const float*)d_in[4];
  const float* w_p2h    = (const float*)d_in[5];
  const float* b_p2h    = (const float*)d_in[6];
  const float* w_enc1   = (const float*)d_in[7];
  const float* b_enc1   = (const float*)d_in[8];
  const float* w_enc2   = (const float*)d_in[9];
  const float* b_enc2   = (const float*)d_in[10];
  const float* w_out    = (const float*)d_in[11];
  const float* b_out    = (const float*)d_in[12];
  const int*   step     = (const int*)d_in[13];
  float* W   = (float*)d_ws;
  float* out = (float*)d_out;

  k_prep_up   <<<49, 256, 0, stream>>>(phases, x, w_p2h, b_p2h, w_enc1, b_enc1, W);
  k_rows      <<<NC / 2, 256, 0, stream>>>(coupling, phases, omegas, Kp, W);
  k_stats_ured<<<4, 1024, 0, stream>>>(W);
  k_cells     <<<128, 256, 0, stream>>>(step, W);
  k_wv        <<<dim3(4, 16), 256, 0, stream>>>(w_enc2, b_enc2, W);
  k_out       <<<dim3(2, 16), 256, 0, stream>>>(w_out, b_out, W, out);
}

// Round 9
// 89.750 us; speedup vs baseline: 19.8438x; 1.0145x over previous
//
#include <hip/hip_runtime.h>
#include <math.h>

// OscillatorEngine on MI355X — round 9.
// Tail (stats/cells/wv/out) = round-8 exact. New: k_prep eliminated —
// k_rows computes the sin/cos table inline per block via __sincosf (kills the
// 4096x64KB L2 table re-read AND the serial prep node; VALU hidden under the
// 64 KB/block HBM stream) and computes ||x|| inline (512 L2 floats + 1 barrier).
// uprep rides as 16 tail blocks of the k_rows grid (fills the drain). 5 nodes.

#define NC   8192
#define DH   1024
#define DIN  512

using f4 = __attribute__((ext_vector_type(4))) float;

// workspace layout (float offsets)
constexpr int TENS = 6, CNT = 7;
constexpr int SNN = 32 + 2 * NC;                 // sin(new phases) [8192]
constexpr int CNN = SNN + NC;
constexpr int UPART  = CNN + NC;                 // [16][3][1024]
constexpr int UFIN   = UPART + 16 * 3 * DH;      // [3][1024]
constexpr int TPART  = UFIN + 3 * DH;            // [128][1024]
constexpr int W2PART = TPART + 128 * DH;         // [16][1024]
constexpr int OPART  = W2PART + 16 * DH;         // [16][512]

__device__ __forceinline__ float frcp(float x) { return __builtin_amdgcn_rcpf(x); }
__device__ __forceinline__ float sigm(float x) { return frcp(1.f + __expf(-x)); }
__device__ __forceinline__ float ftanh(float x) { return 1.f - 2.f * frcp(__expf(2.f * x) + 1.f); }

// K1: blocks 0..4095 = 2 coupling rows each (inline table + inline ||x||);
//     blocks 4096..4111 = u0/u1/u2 partials (tail-fill).
__global__ __launch_bounds__(256) void k_rows_all(const float* __restrict__ coupling,
                                                  const float* __restrict__ phases,
                                                  const float* __restrict__ omegas,
                                                  const float* __restrict__ Kp,
                                                  const float* __restrict__ x,
                                                  const float* __restrict__ w_p2h,
                                                  const float* __restrict__ b_p2h,
                                                  const float* __restrict__ w_enc1,
                                                  const float* __restrict__ b_enc1,
                                                  float* __restrict__ W) {
  int t = threadIdx.x;
  if (blockIdx.x >= 4096) {
    int dy = blockIdx.x - 4096;   // 0..15, d-chunk
    f4 a0 = {0.f, 0.f, 0.f, 0.f}, a1 = a0, a2 = a0;
    for (int d = dy * 64; d < dy * 64 + 64; ++d) {
      f4 r = *(const f4*)(w_enc1 + (size_t)d * DH + 4 * t);
      float s0 = w_p2h[d], s1 = w_p2h[DH + d], s2 = b_p2h[d];
      #pragma unroll
      for (int e = 0; e < 4; ++e) {
        a0[e] = fmaf(s0, r[e], a0[e]);
        a1[e] = fmaf(s1, r[e], a1[e]);
        a2[e] = fmaf(s2, r[e], a2[e]);
      }
    }
    for (int k = dy * 32; k < dy * 32 + 32; ++k) {
      f4 r = *(const f4*)(w_enc1 + (size_t)(DH + k) * DH + 4 * t);
      float xv = x[k];
      #pragma unroll
      for (int e = 0; e < 4; ++e) a2[e] = fmaf(xv, r[e], a2[e]);
    }
    if (dy == 0) {
      f4 bb = *(const f4*)(b_enc1 + 4 * t);
      #pragma unroll
      for (int e = 0; e < 4; ++e) a2[e] += bb[e];
    }
    float* up = W + UPART + dy * 3 * DH;
    *(f4*)(up + 4 * t) = a0;
    *(f4*)(up + DH + 4 * t) = a1;
    *(f4*)(up + 2 * DH + 4 * t) = a2;
    return;
  }
  __shared__ float shn[4];
  __shared__ float sh[4][4];
  int lane = t & 63, w = t >> 6;
  // inline ||x||: 512 floats from L2, butterfly + one barrier
  {
    float x0 = x[t], x1 = x[t + 256];
    float v = x0 * x0 + x1 * x1;
    #pragma unroll
    for (int m = 1; m < 64; m <<= 1) v += __shfl_xor(v, m, 64);
    if (lane == 0) shn[w] = v;
  }
  __syncthreads();
  float img = sqrtf((shn[0] + shn[1]) + (shn[2] + shn[3]));
  int row0 = blockIdx.x * 2;
  const f4* c0 = (const f4*)(coupling + (size_t)row0 * NC);
  const f4* c1 = (const f4*)(coupling + (size_t)(row0 + 1) * NC);
  const f4* p4 = (const f4*)phases;
  float sc0 = 0.f, ss0 = 0.f, sc1 = 0.f, ss1 = 0.f;
  #pragma unroll 2
  for (int k = 0; k < 8; ++k) {
    int idx = k * 256 + t;
    f4 ph = p4[idx];
    f4 v0 = __builtin_nontemporal_load(c0 + idx);
    f4 v1 = __builtin_nontemporal_load(c1 + idx);
    #pragma unroll
    for (int e = 0; e < 4; ++e) {
      float sv, cc;
      __sincosf(ph[e], &sv, &cc);
      float g0 = sigm(v0[e]);
      sc0 = fmaf(g0, cc, sc0);
      ss0 = fmaf(g0, sv, ss0);
      float g1 = sigm(v1[e]);
      sc1 = fmaf(g1, cc, sc1);
      ss1 = fmaf(g1, sv, ss1);
    }
  }
  #pragma unroll
  for (int m = 1; m < 64; m <<= 1) {
    sc0 += __shfl_xor(sc0, m, 64);
    ss0 += __shfl_xor(ss0, m, 64);
    sc1 += __shfl_xor(sc1, m, 64);
    ss1 += __shfl_xor(ss1, m, 64);
  }
  if (lane == 0) { sh[w][0] = sc0; sh[w][1] = ss0; sh[w][2] = sc1; sh[w][3] = ss1; }
  __syncthreads();
  if (t < 2) {
    float sc = sh[0][2 * t] + sh[1][2 * t] + sh[2][2 * t] + sh[3][2 * t];
    float ss = sh[0][2 * t + 1] + sh[1][2 * t + 1] + sh[2][2 * t + 1] + sh[3][2 * t + 1];
    int row = row0 + t;
    float kk = Kp[0];
    float si, ci;
    sincosf(phases[row], &si, &ci);           // precise: output-facing
    float inter = (kk / (float)NC) * (si * sc - ci * ss);
    float dtheta = omegas[row] + inter + 0.1f * img;
    float pn = phases[row] + 0.1f * dtheta;   // mod 2pi dropped: only sin/cos consumed
    float s, c;
    sincosf(pn, &s, &c);
    W[SNN + row] = s;
    W[CNN + row] = c;
  }
}

// K2 (round-8 exact): block 0 = stats; blocks 1..3 = u-partial reduce.
__global__ __launch_bounds__(1024) void k_stats_ured(float* __restrict__ W) {
  if (blockIdx.x > 0) {
    int j = (blockIdx.x - 1) * 1024 + threadIdx.x;  // 0..3071
    float v = 0.f;
    #pragma unroll
    for (int p = 0; p < 16; ++p) v += W[UPART + p * 3 * DH + j];
    W[UFIN + j] = v;
    return;
  }
  __shared__ float shS[16], shC[16], shD[16], shMP[2];
  int t = threadIdx.x, lane = t & 63, w = t >> 6;
  int f = w >> 1, half = w & 1;
  int base = f * 1024 + half * 512;
  float s = 0.f, c = 0.f;
  #pragma unroll
  for (int k = 0; k < 8; ++k) {
    int i = base + k * 64 + lane;
    s += W[SNN + i];
    c += W[CNN + i];
  }
  #pragma unroll
  for (int m = 1; m < 64; m <<= 1) {
    s += __shfl_xor(s, m, 64);
    c += __shfl_xor(c, m, 64);
  }
  if (lane == 0) { shS[w] = s; shC[w] = c; }
  __syncthreads();
  if (t == 0) {
    float ssum = 0.f, csum = 0.f;
    #pragma unroll
    for (int ff = 0; ff < 8; ++ff) {
      float S = shS[2 * ff] + shS[2 * ff + 1];
      float C = shC[2 * ff] + shC[2 * ff + 1];
      W[8 + ff] = S * (1.f / 1024.f);    // SFO
      W[16 + ff] = C * (1.f / 1024.f);   // CFO
      ssum += S;
      csum += C;
    }
    float sbar = ssum * (1.f / (float)NC);
    float cbar = csum * (1.f / (float)NC);
    float mp = atan2f(sbar, cbar);
    float mpc = cosf(mp), mps = sinf(mp);
    W[1] = sbar; W[2] = cbar; W[3] = mpc; W[4] = mps;
    float r = sqrtf(cbar * cbar + sbar * sbar);
    W[TENS] = fabsf(r - 0.5f) * 2.f;
    shMP[0] = mpc; shMP[1] = mps;
  }
  __syncthreads();
  float mpc = shMP[0], mps = shMP[1];
  float d = 0.f;
  #pragma unroll
  for (int k = 0; k < 8; ++k) {
    int i = k * 1024 + t;
    float coh = W[CNN + i] * mpc + W[SNN + i] * mps;
    d += __expf(5.f * coh - 5.f);  // shift by const 5: cancels in normalization
  }
  #pragma unroll
  for (int m = 1; m < 64; m <<= 1) d += __shfl_xor(d, m, 64);
  if (lane == 0) shD[w] = d;
  __syncthreads();
  if (t == 0) {
    float D = 0.f;
    #pragma unroll
    for (int ww = 0; ww < 16; ++ww) D += shD[ww];
    W[5] = D;                          // DEN
  }
}

// K3 (round-8 exact): per-cell rank-2 eval + tanh + weighted accumulate.
__global__ __launch_bounds__(256) void k_cells(const int* __restrict__ step,
                                               float* __restrict__ W) {
  int t = threadIdx.x, b = blockIdx.x;
  float u0[4], u1[4], u2[4], acc[4] = {0.f, 0.f, 0.f, 0.f};
  #pragma unroll
  for (int k = 0; k < 4; ++k) {
    int h = t + k * 256;
    u0[k] = W[UFIN + h];
    u1[k] = W[UFIN + DH + h];
    u2[k] = W[UFIN + 2 * DH + h];
  }
  bool debate = step[0] > 5;
  float sbar = W[1], cbar = W[2], mpc = W[3], mps = W[4];
  float invden = 1.0f / W[5];
  int i0 = b * 64;
  int f = i0 >> 10;  // 64-cell chunk never crosses a faction boundary
  float Sf = W[8 + f], Cf = W[16 + f];
  bool deb = debate && ((i0 & 1023) < 256);  // dc = FS/4 = 256; uniform per chunk
  for (int j = 0; j < 64; ++j) {
    int i = i0 + j;
    float s = W[SNN + i], c = W[CNN + i];
    float a = fmaf(0.15f, Sf, 0.85f * s);
    float bb = fmaf(0.15f, Cf, 0.85f * c);
    if (deb) {
      a = fmaf(0.15f, sbar, 0.85f * a);
      bb = fmaf(0.15f, cbar, 0.85f * bb);
    }
    float coh = c * mpc + s * mps;
    float wgt = __expf(5.f * coh - 5.f) * invden;
    #pragma unroll
    for (int k = 0; k < 4; ++k) {
      float pre = fmaf(a, u0[k], fmaf(bb, u1[k], u2[k]));
      acc[k] = fmaf(wgt, ftanh(pre), acc[k]);
    }
  }
  #pragma unroll
  for (int k = 0; k < 4; ++k) W[TPART + b * DH + t + k * 256] = acc[k];
}

// K4 (round-8 exact): t_sum reduce + matvec w_enc2.
__global__ __launch_bounds__(256) void k_wv(const float* __restrict__ w_enc2,
                                            const float* __restrict__ b_enc2,
                                            float* __restrict__ W) {
  __shared__ float ts[64];
  int t = threadIdx.x, cb = blockIdx.x, hb = blockIdx.y;
  if (t == 0 && cb == 0 && hb == 0) *(unsigned*)(W + CNT) = 0u;
  if (t < 64) {
    int h = hb * 64 + t;
    float v = 0.f;
    for (int p = 0; p < 128; ++p) v += W[TPART + p * DH + h];
    ts[t] = v;
  }
  __syncthreads();
  int c = cb * 256 + t;
  float acc = (hb == 0) ? b_enc2[c] : 0.f;
  #pragma unroll 8
  for (int j = 0; j < 64; ++j) acc = fmaf(ts[j], w_enc2[(hb * 64 + j) * DH + c], acc);
  W[W2PART + hb * DH + c] = acc;
}

// K5 (round-8 exact): weighted reduce + matvec w_out; last block does final.
__global__ __launch_bounds__(256) void k_out(const float* __restrict__ w_out,
                                             const float* __restrict__ b_out,
                                             float* __restrict__ W,
                                             float* __restrict__ out) {
  __shared__ float wv[64];
  __shared__ int last;
  int t = threadIdx.x, ob = blockIdx.x, cb = blockIdx.y;
  if (t < 64) {
    int c = cb * 64 + t;
    float v = 0.f;
    #pragma unroll
    for (int p = 0; p < 16; ++p) v += W[W2PART + p * DH + c];
    wv[t] = v;
  }
  __syncthreads();
  int o = ob * 256 + t;
  float acc = 0.f;
  #pragma unroll 8
  for (int j = 0; j < 64; ++j) acc = fmaf(wv[j], w_out[(cb * 64 + j) * DIN + o], acc);
  W[OPART + cb * DIN + o] = acc;
  __syncthreads();
  if (t == 0) {
    unsigned old = __hip_atomic_fetch_add((unsigned*)(W + CNT), 1u,
                                          __ATOMIC_ACQ_REL, __HIP_MEMORY_SCOPE_AGENT);
    last = (old == 31u);
  }
  __syncthreads();
  if (!last) return;
  for (int oo = t; oo < DIN; oo += 256) {
    float a = b_out[oo];
    #pragma unroll
    for (int p = 0; p < 16; ++p) a += W[OPART + p * DIN + oo];
    out[oo] = a;
  }
  if (t == 0) out[DIN] = W[TENS];
}

extern "C" void kernel_launch(void* const* d_in, const int* in_sizes, int n_in,
                              void* d_out, int out_size, void* d_ws, size_t ws_size,
                              hipStream_t stream) {
  (void)in_sizes; (void)n_in; (void)out_size; (void)ws_size;
  const float* x        = (const float*)d_in[0];
  const float* phases   = (const float*)d_in[1];
  const float* omegas   = (const float*)d_in[2];
  const float* coupling = (const float*)d_in[3];
  const float* Kp       = (const float*)d_in[4];
  const float* w_p2h    = (const float*)d_in[5];
  const float* b_p2h    = (const float*)d_in[6];
  const float* w_enc1   = (const float*)d_in[7];
  const float* b_enc1   = (const float*)d_in[8];
  const float* w_enc2   = (const float*)d_in[9];
  const float* b_enc2   = (const float*)d_in[10];
  const float* w_out    = (const float*)d_in[11];
  const float* b_out    = (const float*)d_in[12];
  const int*   step     = (const int*)d_in[13];
  float* W   = (float*)d_ws;
  float* out = (float*)d_out;

  k_rows_all  <<<4112, 256, 0, stream>>>(coupling, phases, omegas, Kp, x,
                                         w_p2h, b_p2h, w_enc1, b_enc1, W);
  k_stats_ured<<<4, 1024, 0, stream>>>(W);
  k_cells     <<<128, 256, 0, stream>>>(step, W);
  k_wv        <<<dim3(4, 16), 256, 0, stream>>>(w_enc2, b_enc2, W);
  k_out       <<<dim3(2, 16), 256, 0, stream>>>(w_out, b_out, W, out);
}